// Round 1
// 105.917 us; speedup vs baseline: 1.1314x; 1.1314x over previous
//
#include <hip/hip_runtime.h>

#define BB 4
#define CC 64
#define OO 64
#define HH 128
#define WW 128
#define HP 131          // padded rows (0..130 valid)
#define WP 132          // padded row width
#define HW (HH*WW)

#define TH 8            // output tile rows per block
#define TW 8            // output tile cols per block
#define WR 15           // staged window rows
#define WC 15           // staged window cols
#define NWIN (WR*WC)    // 225
#define PXS 36          // LDS dwords per window pixel (32 ch-pairs + 4 pad)

typedef __attribute__((ext_vector_type(8))) short short8;
typedef __attribute__((ext_vector_type(4))) float f32x4;

__device__ __forceinline__ unsigned f2b(float f) {  // RNE float->bf16 bits (host-side tables)
  unsigned u = __float_as_uint(f);
  return (u + 0x7fffu + ((u >> 16) & 1u)) >> 16;
}
// HW RNE pack: identical rounding to f2b pair, 1 instruction instead of ~10.
__device__ __forceinline__ unsigned cvtpk(float lo, float hi) {
  unsigned r;
  asm("v_cvt_pk_bf16_f32 %0, %1, %2" : "=v"(r) : "v"(lo), "v"(hi));
  return r;
}
__device__ __forceinline__ float blo(unsigned r) { return __uint_as_float(r << 16); }
__device__ __forceinline__ float bhi(unsigned r) { return __uint_as_float(r & 0xffff0000u); }

__device__ __forceinline__ short8 lerp8(uint4 q00, uint4 q01, uint4 q10, uint4 q11,
                                        float ww0, float ww1, float wh0, float wh1) {
  unsigned c00[4] = {q00.x, q00.y, q00.z, q00.w};
  unsigned c01[4] = {q01.x, q01.y, q01.z, q01.w};
  unsigned c10[4] = {q10.x, q10.y, q10.z, q10.w};
  unsigned c11[4] = {q11.x, q11.y, q11.z, q11.w};
  union { unsigned u[4]; short8 v; } A;
#pragma unroll
  for (int t = 0; t < 4; ++t) {
    float tL = fmaf(blo(c01[t]), ww1, blo(c00[t]) * ww0);
    float bL = fmaf(blo(c11[t]), ww1, blo(c10[t]) * ww0);
    float tH = fmaf(bhi(c01[t]), ww1, bhi(c00[t]) * ww0);
    float bH = fmaf(bhi(c11[t]), ww1, bhi(c10[t]) * ww0);
    A.u[t] = cvtpk(fmaf(bL, wh1, tL * wh0), fmaf(bH, wh1, tH * wh0));
  }
  return A.v;
}

// ---------------- pad + bf16 + CHANNEL-LAST: xp[b][hp][wp][c2] ----------------
__global__ __launch_bounds__(256) void pad_kernel(const float* __restrict__ x,
                                                  unsigned* __restrict__ xp) {
  int i = blockIdx.x * 256 + threadIdx.x;       // (b,hp,wp,c8)
  if (i >= BB * HP * WP * 8) return;
  int c8 = i & 7;
  int t = i >> 3;
  int wp = t % WP;
  int t2 = t / WP;
  int hp = t2 % HP;
  int b = t2 / HP;
  uint4 v = make_uint4(0, 0, 0, 0);
  if (hp >= 1 && hp <= HH && wp >= 1 && wp <= WW) {
    const float* s = x + (((size_t)(b * CC + c8 * 8)) * HH + (hp - 1)) * WW + (wp - 1);
    v.x = cvtpk(s[0], s[HW]);
    v.y = cvtpk(s[2 * HW], s[3 * HW]);
    v.z = cvtpk(s[4 * HW], s[5 * HW]);
    v.w = cvtpk(s[6 * HW], s[7 * HW]);
  }
  *(uint4*)(xp + (size_t)t * 32 + c8 * 4) = v;
}

// ---------------- weight repack: MFMA-FRAGMENT ORDER ----------------
// main: tile T=(kk*2+sh)*4+nt (72 tiles); within tile lane L stores 8 bf16:
//   o = nt*16 + (L&15), c = sh*32 + (L>>4)*8 + j  ->  wbf[T*512 + L*8 + j]
// offs: tile T=(kk*2+sh)*2+nt (36 tiles), rows oc>=18 zero.
__global__ __launch_bounds__(256) void repackw_kernel(const float* __restrict__ wt,
                                                      const float* __restrict__ ow,
                                                      ushort* __restrict__ wbf,
                                                      ushort* __restrict__ owbf) {
  int i = blockIdx.x * 256 + threadIdx.x;
  if (i < 72 * 512) {
    int j = i & 7, lane = (i >> 3) & 63, T = i >> 9;
    int nt = T & 3, sh = (T >> 2) & 1, kk = T >> 3;
    int o = nt * 16 + (lane & 15);
    int c = sh * 32 + (lane >> 4) * 8 + j;
    wbf[i] = (ushort)f2b(wt[(o * CC + c) * 9 + kk]);
  } else if (i < 72 * 512 + 36 * 512) {
    int i2 = i - 72 * 512;
    int j = i2 & 7, lane = (i2 >> 3) & 63, T = i2 >> 9;
    int nt = T & 1, sh = (T >> 1) & 1, kk = T >> 2;
    int oc = nt * 16 + (lane & 15);
    int c = sh * 32 + (lane >> 4) * 8 + j;
    owbf[i2] = (oc < 18) ? (ushort)f2b(ow[(oc * CC + c) * 9 + kk]) : (ushort)0;
  }
}

// ---------------- fused: stage window -> offs GEMM -> deform GEMM ----------------
// kk-outer everywhere: batch 8 B-tile L2 loads per tap BEFORE the LDS gather+lerp
// so their latency hides under ~400cy of VALU. All loops statically unrolled
// (incl. cold path) so ph/pw/orow stay in registers — no scratch.
__global__ __launch_bounds__(256, 4) void fused_deform(const unsigned* __restrict__ xp,
                                                       const ushort* __restrict__ wbf,
                                                       const ushort* __restrict__ owbf,
                                                       const float* __restrict__ obias,
                                                       const float* __restrict__ bias,
                                                       float* __restrict__ out) {
  __shared__ __align__(16) unsigned win[NWIN * PXS];   // 32.4 KB
  __shared__ __align__(16) float obuf[64 * 20];        // 5.1 KB

  int tid = threadIdx.x;
  int blk0 = blockIdx.x;
  int xcd = blk0 & 7, i = blk0 >> 3;
  int s = xcd * 8 + (i >> 4);            // slab 0..63 = b*16 + ht
  int b = s >> 4, ht = s & 15, wtile = i & 15;
  int H0 = ht * TH, W0 = wtile * TW;
  int rlo = H0 - 1, clo = W0 - 1;        // window origin, padded coords

  int wave = tid >> 6, lane = tid & 63, lm = lane & 15, lq = lane >> 4;
  const unsigned* xpb = xp + (size_t)b * (HP * WP * 32);

  // ---- stage window: batch all global loads, then all LDS writes ----
  {
    uint4 sv[8];
#pragma unroll
    for (int it = 0; it < 8; ++it) {
      int q = tid + it * 256;
      uint4 v = make_uint4(0, 0, 0, 0);
      if (q < NWIN * 8) {
        int px = q >> 3;
        int r = px / WC, c = px % WC;
        int pr = rlo + r, pc = clo + c;
        if (pr >= 0 && pr <= HP - 1 && pc >= 0 && pc <= WP - 2)
          v = *(const uint4*)(xpb + ((size_t)pr * WP + pc) * 32 + (q & 7) * 4);
      }
      sv[it] = v;
    }
#pragma unroll
    for (int it = 0; it < 8; ++it) {
      int q = tid + it * 256;
      if (q < NWIN * 8) {
        int px = q >> 3, ch = q & 7;
        *(uint4*)&win[px * PXS + ch * 4] = sv[it];
      }
    }
  }
  __syncthreads();

  int row = 2 * wave + (lm >> 3);        // tile-local pixel coords for lane lm
  int col = lm & 7;
  int h = H0 + row, w = W0 + col;

  // ---- offs GEMM, kk-outer: 4 batched B loads + 2 LDS A reads + 4 MFMAs ----
  {
    f32x4 oacc0 = (f32x4)0.0f, oacc1 = (f32x4)0.0f;
#pragma unroll
    for (int kk = 0; kk < 9; ++kk) {
      const ushort* obp = owbf + (size_t)(kk * 4) * 512 + lane * 8;
      short8 ob00 = *(const short8*)(obp);            // sh0,nt0
      short8 ob01 = *(const short8*)(obp + 512);      // sh0,nt1
      short8 ob10 = *(const short8*)(obp + 1024);     // sh1,nt0
      short8 ob11 = *(const short8*)(obp + 1536);     // sh1,nt1
      int kh = kk / 3, kw = kk % 3;
      int widx = (row + kh + 1) * WC + (col + kw + 1);
      const unsigned* wp0 = &win[widx * PXS + lq * 4];
      short8 Ao0 = *(const short8*)wp0;
      short8 Ao1 = *(const short8*)(wp0 + 16);
      oacc0 = __builtin_amdgcn_mfma_f32_16x16x32_bf16(Ao0, ob00, oacc0, 0, 0, 0);
      oacc1 = __builtin_amdgcn_mfma_f32_16x16x32_bf16(Ao0, ob01, oacc1, 0, 0, 0);
      oacc0 = __builtin_amdgcn_mfma_f32_16x16x32_bf16(Ao1, ob10, oacc0, 0, 0, 0);
      oacc1 = __builtin_amdgcn_mfma_f32_16x16x32_bf16(Ao1, ob11, oacc1, 0, 0, 0);
    }
#pragma unroll
    for (int nt = 0; nt < 2; ++nt) {
      f32x4 oa = nt ? oacc1 : oacc0;
      int oc = nt * 16 + lm;
      if (oc < 18) {
        float bv = obias[oc];
        int idx = (oc < 9) ? (oc * 2) : ((oc - 9) * 2 + 1);
#pragma unroll
        for (int r2 = 0; r2 < 4; ++r2)
          obuf[(wave * 16 + lq * 4 + r2) * 20 + idx] = oa[r2] + bv;
      }
    }
  }
  __syncthreads();

  // ---- positions once (statically indexed everywhere -> registers) ----
  float ph[9], pw[9];
  bool okall = true;
  {
    float orow[20];
    const float* orp = &obuf[(wave * 16 + lm) * 20];
#pragma unroll
    for (int q = 0; q < 5; ++q) *(float4*)&orow[q * 4] = *(const float4*)(orp + q * 4);
#pragma unroll
    for (int kk = 0; kk < 9; ++kk) {
      int kh = kk / 3, kw = kk % 3;
      float p_h = (((float)kh + orow[kk * 2]) + (float)h) + 1.0f;
      float p_w = (((float)kw + orow[kk * 2 + 1]) + (float)w) + 1.0f;
      p_h = fminf(fmaxf(p_h, 0.0f), 129.0f);
      p_w = fminf(fmaxf(p_w, 0.0f), 129.0f);
      ph[kk] = p_h;
      pw[kk] = p_w;
      int h0 = (int)floorf(p_h), w0 = (int)floorf(p_w);
      int wr0 = h0 - rlo, wc0 = w0 - clo;
      okall &= (wr0 >= 0) & (wr0 <= WR - 2) & (wc0 >= 0) & (wc0 <= WC - 2);
    }
  }

  f32x4 acc[4];
#pragma unroll
  for (int nt = 0; nt < 4; ++nt) acc[nt] = (f32x4)0.0f;

  if (__builtin_amdgcn_ballot_w64(okall) == ~0ull) {
    // ---- fast path, kk-outer: 8 B loads in flight over gather+lerp ----
#pragma unroll
    for (int kk = 0; kk < 9; ++kk) {
      const ushort* bp = wbf + (size_t)kk * 4096 + lane * 8;
      short8 b00 = *(const short8*)(bp);
      short8 b01 = *(const short8*)(bp + 512);
      short8 b02 = *(const short8*)(bp + 1024);
      short8 b03 = *(const short8*)(bp + 1536);
      short8 b10 = *(const short8*)(bp + 2048);
      short8 b11 = *(const short8*)(bp + 2560);
      short8 b12 = *(const short8*)(bp + 3072);
      short8 b13 = *(const short8*)(bp + 3584);

      float p_h = ph[kk], p_w = pw[kk];
      float fh0 = floorf(p_h), fw0 = floorf(p_w);
      int h0 = (int)fh0, w0 = (int)fw0;
      float wh1 = p_h - fh0, ww1 = p_w - fw0;
      float wh0 = 1.0f - wh1, ww0 = 1.0f - ww1;
      const unsigned* pA = &win[((h0 - rlo) * WC + (w0 - clo)) * PXS + lq * 4];
      uint4 q00a = *(const uint4*)pA;
      uint4 q01a = *(const uint4*)(pA + PXS);
      uint4 q10a = *(const uint4*)(pA + WC * PXS);
      uint4 q11a = *(const uint4*)(pA + WC * PXS + PXS);
      uint4 q00b = *(const uint4*)(pA + 16);
      uint4 q01b = *(const uint4*)(pA + PXS + 16);
      uint4 q10b = *(const uint4*)(pA + WC * PXS + 16);
      uint4 q11b = *(const uint4*)(pA + WC * PXS + PXS + 16);
      short8 Af0 = lerp8(q00a, q01a, q10a, q11a, ww0, ww1, wh0, wh1);
      short8 Af1 = lerp8(q00b, q01b, q10b, q11b, ww0, ww1, wh0, wh1);

      acc[0] = __builtin_amdgcn_mfma_f32_16x16x32_bf16(Af0, b00, acc[0], 0, 0, 0);
      acc[1] = __builtin_amdgcn_mfma_f32_16x16x32_bf16(Af0, b01, acc[1], 0, 0, 0);
      acc[2] = __builtin_amdgcn_mfma_f32_16x16x32_bf16(Af0, b02, acc[2], 0, 0, 0);
      acc[3] = __builtin_amdgcn_mfma_f32_16x16x32_bf16(Af0, b03, acc[3], 0, 0, 0);
      acc[0] = __builtin_amdgcn_mfma_f32_16x16x32_bf16(Af1, b10, acc[0], 0, 0, 0);
      acc[1] = __builtin_amdgcn_mfma_f32_16x16x32_bf16(Af1, b11, acc[1], 0, 0, 0);
      acc[2] = __builtin_amdgcn_mfma_f32_16x16x32_bf16(Af1, b12, acc[2], 0, 0, 0);
      acc[3] = __builtin_amdgcn_mfma_f32_16x16x32_bf16(Af1, b13, acc[3], 0, 0, 0);
    }
  } else {
    // ---- cold exact path (not taken for this data): per-tap global xp gather.
    // FULLY UNROLLED so ph/pw indexing stays static (no scratch allocation). ----
#pragma unroll
    for (int kk = 0; kk < 9; ++kk) {
      float p_h = ph[kk], p_w = pw[kk];
      float fh0 = floorf(p_h), fw0 = floorf(p_w);
      int h0 = (int)fh0, w0 = (int)fw0;
      float wh1 = p_h - fh0, ww1 = p_w - fw0;
      float wh0 = 1.0f - wh1, ww0 = 1.0f - ww1;
      const unsigned* pG = xpb + ((size_t)h0 * WP + w0) * 32 + lq * 4;
      uint4 q00a = *(const uint4*)pG;
      uint4 q01a = *(const uint4*)(pG + 32);
      uint4 q10a = *(const uint4*)(pG + WP * 32);
      uint4 q11a = *(const uint4*)(pG + WP * 32 + 32);
      uint4 q00b = *(const uint4*)(pG + 16);
      uint4 q01b = *(const uint4*)(pG + 48);
      uint4 q10b = *(const uint4*)(pG + WP * 32 + 16);
      uint4 q11b = *(const uint4*)(pG + WP * 32 + 48);
      short8 A0v = lerp8(q00a, q01a, q10a, q11a, ww0, ww1, wh0, wh1);
      short8 A1v = lerp8(q00b, q01b, q10b, q11b, ww0, ww1, wh0, wh1);
      const ushort* bp = wbf + (size_t)kk * 4096 + lane * 8;
      acc[0] = __builtin_amdgcn_mfma_f32_16x16x32_bf16(A0v, *(const short8*)(bp), acc[0], 0, 0, 0);
      acc[1] = __builtin_amdgcn_mfma_f32_16x16x32_bf16(A0v, *(const short8*)(bp + 512), acc[1], 0, 0, 0);
      acc[2] = __builtin_amdgcn_mfma_f32_16x16x32_bf16(A0v, *(const short8*)(bp + 1024), acc[2], 0, 0, 0);
      acc[3] = __builtin_amdgcn_mfma_f32_16x16x32_bf16(A0v, *(const short8*)(bp + 1536), acc[3], 0, 0, 0);
      acc[0] = __builtin_amdgcn_mfma_f32_16x16x32_bf16(A1v, *(const short8*)(bp + 2048), acc[0], 0, 0, 0);
      acc[1] = __builtin_amdgcn_mfma_f32_16x16x32_bf16(A1v, *(const short8*)(bp + 2560), acc[1], 0, 0, 0);
      acc[2] = __builtin_amdgcn_mfma_f32_16x16x32_bf16(A1v, *(const short8*)(bp + 3072), acc[2], 0, 0, 0);
      acc[3] = __builtin_amdgcn_mfma_f32_16x16x32_bf16(A1v, *(const short8*)(bp + 3584), acc[3], 0, 0, 0);
    }
  }

  // ---- epilogue ----
  {
    int px0 = lq * 4;
    int hrow = H0 + 2 * wave + (px0 >> 3);
    int wcol = W0 + (px0 & 7);
#pragma unroll
    for (int nt = 0; nt < 4; ++nt) {
      int o = nt * 16 + lm;
      float bv = bias[o];
      float4 st = make_float4(acc[nt][0] + bv, acc[nt][1] + bv, acc[nt][2] + bv, acc[nt][3] + bv);
      *(float4*)(out + ((size_t)(b * OO + o) * HH + hrow) * WW + wcol) = st;
    }
  }
}

extern "C" void kernel_launch(void* const* d_in, const int* in_sizes, int n_in,
                              void* d_out, int out_size, void* d_ws, size_t ws_size,
                              hipStream_t stream) {
  const float* x        = (const float*)d_in[0];
  const float* weight   = (const float*)d_in[1];
  const float* bias     = (const float*)d_in[2];
  const float* offset_w = (const float*)d_in[3];
  const float* offset_b = (const float*)d_in[4];
  float* out = (float*)d_out;

  unsigned* xp  = (unsigned*)d_ws;                          // 4*131*132*32 uints = 8.85 MB
  ushort* wbf  = (ushort*)(xp + (size_t)BB * HP * WP * 32); // 72*512 ushorts
  ushort* owbf = wbf + (size_t)72 * 512;                    // 36*512 ushorts

  pad_kernel<<<(BB * HP * WP * 8 + 255) / 256, 256, 0, stream>>>(x, xp);
  repackw_kernel<<<(72 * 512 + 36 * 512 + 255) / 256, 256, 0, stream>>>(weight, offset_w, wbf, owbf);
  fused_deform<<<1024, 256, 0, stream>>>(xp, wbf, owbf, offset_b, bias, out);
}

// Round 4
// 101.099 us; speedup vs baseline: 1.1853x; 1.0477x over previous
//
#include <hip/hip_runtime.h>

#define BB 4
#define CC 64
#define OO 64
#define HH 128
#define WW 128
#define HP 131          // padded rows (0..130 valid; 0,129,130 zero)
#define WP 132          // padded row width (1..128 data, rest zero)
#define HW (HH*WW)

#define TH 8            // output tile rows per block
#define TW 8            // output tile cols per block
#define WR 15           // staged window rows
#define WC 15           // staged window cols
#define NWIN (WR*WC)    // 225
#define PXS 36          // LDS dwords per window pixel (32 ch-pairs + 4 pad)

typedef __attribute__((ext_vector_type(8))) short short8;
typedef __attribute__((ext_vector_type(4))) float f32x4;

__device__ __forceinline__ unsigned f2b(float f) {  // RNE float->bf16 bits (weight tables)
  unsigned u = __float_as_uint(f);
  return (u + 0x7fffu + ((u >> 16) & 1u)) >> 16;
}
// HW RNE pack: identical rounding to f2b pair, 1 instruction.
__device__ __forceinline__ unsigned cvtpk(float lo, float hi) {
  unsigned r;
  asm("v_cvt_pk_bf16_f32 %0, %1, %2" : "=v"(r) : "v"(lo), "v"(hi));
  return r;
}
__device__ __forceinline__ float blo(unsigned r) { return __uint_as_float(r << 16); }
__device__ __forceinline__ float bhi(unsigned r) { return __uint_as_float(r & 0xffff0000u); }

__device__ __forceinline__ short8 lerp8(uint4 q00, uint4 q01, uint4 q10, uint4 q11,
                                        float ww0, float ww1, float wh0, float wh1) {
  unsigned c00[4] = {q00.x, q00.y, q00.z, q00.w};
  unsigned c01[4] = {q01.x, q01.y, q01.z, q01.w};
  unsigned c10[4] = {q10.x, q10.y, q10.z, q10.w};
  unsigned c11[4] = {q11.x, q11.y, q11.z, q11.w};
  union { unsigned u[4]; short8 v; } A;
#pragma unroll
  for (int t = 0; t < 4; ++t) {
    float tL = fmaf(blo(c01[t]), ww1, blo(c00[t]) * ww0);
    float bL = fmaf(blo(c11[t]), ww1, blo(c10[t]) * ww0);
    float tH = fmaf(bhi(c01[t]), ww1, bhi(c00[t]) * ww0);
    float bH = fmaf(bhi(c11[t]), ww1, bhi(c10[t]) * ww0);
    A.u[t] = cvtpk(fmaf(bL, wh1, tL * wh0), fmaf(bH, wh1, tH * wh0));
  }
  return A.v;
}

// ================= prep: row-transpose pad + weight repack, ONE launch =================
// blocks [0,512): one (b,h) source row -> xp[hp][wp][c2] bf16, coalesced both sides
// blocks [512,524): zero rows hp in {0,129,130} x 4 batches
// blocks [524,740): weight repack into MFMA-fragment order
#define NROW (BB*HH)          // 512
#define NZB  12
#define NRPK 216              // (72*512+36*512)/256

__global__ __launch_bounds__(256) void prep_kernel(const float* __restrict__ x,
                                                   const float* __restrict__ wt,
                                                   const float* __restrict__ ow,
                                                   unsigned* __restrict__ xp,
                                                   ushort* __restrict__ wbf,
                                                   ushort* __restrict__ owbf) {
  __shared__ float rbuf[64 * 129];   // stride 129: bank = (c+w)%32 -> 2-way max (free)
  int bid = blockIdx.x;
  int tid = threadIdx.x;

  if (bid < NROW) {
    int b = bid >> 7, h = bid & 127;
    const float* xs = x + ((size_t)b * CC * HH + h) * WW;  // element (c,w) at c*HW + w
#pragma unroll
    for (int it = 0; it < 32; ++it) {          // 64*128 floats, coalesced 256B runs
      int idx = it * 256 + tid;
      int c = idx >> 7, w = idx & 127;
      rbuf[c * 129 + w] = xs[(size_t)c * HW + w];
    }
    __syncthreads();
    int hp = h + 1;
    unsigned* xrow = xp + (size_t)b * (HP * WP * 32) + (size_t)hp * (WP * 32);
#pragma unroll
    for (int it = 0; it < 5; ++it) {           // 132 wp * 8 c8 uint4 writes, coalesced
      int q = it * 256 + tid;
      if (q < WP * 8) {
        int wp = q >> 3, c8 = q & 7;
        uint4 v = make_uint4(0, 0, 0, 0);
        if (wp >= 1 && wp <= WW) {
          const float* rp = &rbuf[(c8 * 8) * 129 + (wp - 1)];
          v.x = cvtpk(rp[0], rp[129]);
          v.y = cvtpk(rp[2 * 129], rp[3 * 129]);
          v.z = cvtpk(rp[4 * 129], rp[5 * 129]);
          v.w = cvtpk(rp[6 * 129], rp[7 * 129]);
        }
        *(uint4*)(xrow + (size_t)wp * 32 + c8 * 4) = v;
      }
    }
  } else if (bid < NROW + NZB) {
    int z = bid - NROW;
    int b = z / 3, r = z % 3;
    int hp = (r == 0) ? 0 : ((r == 1) ? 129 : 130);
    unsigned* xrow = xp + (size_t)b * (HP * WP * 32) + (size_t)hp * (WP * 32);
    for (int q = tid; q < WP * 8; q += 256)
      *(uint4*)(xrow + (size_t)(q >> 3) * 32 + (q & 7) * 4) = make_uint4(0, 0, 0, 0);
  } else {
    int i = (bid - NROW - NZB) * 256 + tid;
    if (i < 72 * 512) {
      int j = i & 7, lane = (i >> 3) & 63, T = i >> 9;
      int nt = T & 3, sh = (T >> 2) & 1, kk = T >> 3;
      int o = nt * 16 + (lane & 15);
      int c = sh * 32 + (lane >> 4) * 8 + j;
      wbf[i] = (ushort)f2b(wt[(o * CC + c) * 9 + kk]);
    } else if (i < 72 * 512 + 36 * 512) {
      int i2 = i - 72 * 512;
      int j = i2 & 7, lane = (i2 >> 3) & 63, T = i2 >> 9;
      int nt = T & 1, sh = (T >> 1) & 1, kk = T >> 2;
      int oc = nt * 16 + (lane & 15);
      int c = sh * 32 + (lane >> 4) * 8 + j;
      owbf[i2] = (oc < 18) ? (ushort)f2b(ow[(oc * CC + c) * 9 + kk]) : (ushort)0;
    }
  }
}

// ---------------- fused: stage window -> offs GEMM -> deform GEMM ----------------
// (round-1 verbatim: kk-outer, batched B loads, all loops statically unrolled)
__global__ __launch_bounds__(256, 4) void fused_deform(const unsigned* __restrict__ xp,
                                                       const ushort* __restrict__ wbf,
                                                       const ushort* __restrict__ owbf,
                                                       const float* __restrict__ obias,
                                                       const float* __restrict__ bias,
                                                       float* __restrict__ out) {
  __shared__ __align__(16) unsigned win[NWIN * PXS];   // 32.4 KB
  __shared__ __align__(16) float obuf[64 * 20];        // 5.1 KB

  int tid = threadIdx.x;
  int blk0 = blockIdx.x;
  int xcd = blk0 & 7, i = blk0 >> 3;
  int s = xcd * 8 + (i >> 4);            // slab 0..63 = b*16 + ht
  int b = s >> 4, ht = s & 15, wtile = i & 15;
  int H0 = ht * TH, W0 = wtile * TW;
  int rlo = H0 - 1, clo = W0 - 1;        // window origin, padded coords

  int wave = tid >> 6, lane = tid & 63, lm = lane & 15, lq = lane >> 4;
  const unsigned* xpb = xp + (size_t)b * (HP * WP * 32);

  // ---- stage window: batch all global loads, then all LDS writes ----
  {
    uint4 sv[8];
#pragma unroll
    for (int it = 0; it < 8; ++it) {
      int q = tid + it * 256;
      uint4 v = make_uint4(0, 0, 0, 0);
      if (q < NWIN * 8) {
        int px = q >> 3;
        int r = px / WC, c = px % WC;
        int pr = rlo + r, pc = clo + c;
        if (pr >= 0 && pr <= HP - 1 && pc >= 0 && pc <= WP - 2)
          v = *(const uint4*)(xpb + ((size_t)pr * WP + pc) * 32 + (q & 7) * 4);
      }
      sv[it] = v;
    }
#pragma unroll
    for (int it = 0; it < 8; ++it) {
      int q = tid + it * 256;
      if (q < NWIN * 8) {
        int px = q >> 3, ch = q & 7;
        *(uint4*)&win[px * PXS + ch * 4] = sv[it];
      }
    }
  }
  __syncthreads();

  int row = 2 * wave + (lm >> 3);        // tile-local pixel coords for lane lm
  int col = lm & 7;
  int h = H0 + row, w = W0 + col;

  // ---- offs GEMM, kk-outer: 4 batched B loads + 2 LDS A reads + 4 MFMAs ----
  {
    f32x4 oacc0 = (f32x4)0.0f, oacc1 = (f32x4)0.0f;
#pragma unroll
    for (int kk = 0; kk < 9; ++kk) {
      const ushort* obp = owbf + (size_t)(kk * 4) * 512 + lane * 8;
      short8 ob00 = *(const short8*)(obp);            // sh0,nt0
      short8 ob01 = *(const short8*)(obp + 512);      // sh0,nt1
      short8 ob10 = *(const short8*)(obp + 1024);     // sh1,nt0
      short8 ob11 = *(const short8*)(obp + 1536);     // sh1,nt1
      int kh = kk / 3, kw = kk % 3;
      int widx = (row + kh + 1) * WC + (col + kw + 1);
      const unsigned* wp0 = &win[widx * PXS + lq * 4];
      short8 Ao0 = *(const short8*)wp0;
      short8 Ao1 = *(const short8*)(wp0 + 16);
      oacc0 = __builtin_amdgcn_mfma_f32_16x16x32_bf16(Ao0, ob00, oacc0, 0, 0, 0);
      oacc1 = __builtin_amdgcn_mfma_f32_16x16x32_bf16(Ao0, ob01, oacc1, 0, 0, 0);
      oacc0 = __builtin_amdgcn_mfma_f32_16x16x32_bf16(Ao1, ob10, oacc0, 0, 0, 0);
      oacc1 = __builtin_amdgcn_mfma_f32_16x16x32_bf16(Ao1, ob11, oacc1, 0, 0, 0);
    }
#pragma unroll
    for (int nt = 0; nt < 2; ++nt) {
      f32x4 oa = nt ? oacc1 : oacc0;
      int oc = nt * 16 + lm;
      if (oc < 18) {
        float bv = obias[oc];
        int idx = (oc < 9) ? (oc * 2) : ((oc - 9) * 2 + 1);
#pragma unroll
        for (int r2 = 0; r2 < 4; ++r2)
          obuf[(wave * 16 + lq * 4 + r2) * 20 + idx] = oa[r2] + bv;
      }
    }
  }
  __syncthreads();

  // ---- positions once (statically indexed everywhere -> registers) ----
  float ph[9], pw[9];
  bool okall = true;
  {
    float orow[20];
    const float* orp = &obuf[(wave * 16 + lm) * 20];
#pragma unroll
    for (int q = 0; q < 5; ++q) *(float4*)&orow[q * 4] = *(const float4*)(orp + q * 4);
#pragma unroll
    for (int kk = 0; kk < 9; ++kk) {
      int kh = kk / 3, kw = kk % 3;
      float p_h = (((float)kh + orow[kk * 2]) + (float)h) + 1.0f;
      float p_w = (((float)kw + orow[kk * 2 + 1]) + (float)w) + 1.0f;
      p_h = fminf(fmaxf(p_h, 0.0f), 129.0f);
      p_w = fminf(fmaxf(p_w, 0.0f), 129.0f);
      ph[kk] = p_h;
      pw[kk] = p_w;
      int h0 = (int)floorf(p_h), w0 = (int)floorf(p_w);
      int wr0 = h0 - rlo, wc0 = w0 - clo;
      okall &= (wr0 >= 0) & (wr0 <= WR - 2) & (wc0 >= 0) & (wc0 <= WC - 2);
    }
  }

  f32x4 acc[4];
#pragma unroll
  for (int nt = 0; nt < 4; ++nt) acc[nt] = (f32x4)0.0f;

  if (__builtin_amdgcn_ballot_w64(okall) == ~0ull) {
    // ---- fast path, kk-outer: 8 B loads in flight over gather+lerp ----
#pragma unroll
    for (int kk = 0; kk < 9; ++kk) {
      const ushort* bp = wbf + (size_t)kk * 4096 + lane * 8;
      short8 b00 = *(const short8*)(bp);
      short8 b01 = *(const short8*)(bp + 512);
      short8 b02 = *(const short8*)(bp + 1024);
      short8 b03 = *(const short8*)(bp + 1536);
      short8 b10 = *(const short8*)(bp + 2048);
      short8 b11 = *(const short8*)(bp + 2560);
      short8 b12 = *(const short8*)(bp + 3072);
      short8 b13 = *(const short8*)(bp + 3584);

      float p_h = ph[kk], p_w = pw[kk];
      float fh0 = floorf(p_h), fw0 = floorf(p_w);
      int h0 = (int)fh0, w0 = (int)fw0;
      float wh1 = p_h - fh0, ww1 = p_w - fw0;
      float wh0 = 1.0f - wh1, ww0 = 1.0f - ww1;
      const unsigned* pA = &win[((h0 - rlo) * WC + (w0 - clo)) * PXS + lq * 4];
      uint4 q00a = *(const uint4*)pA;
      uint4 q01a = *(const uint4*)(pA + PXS);
      uint4 q10a = *(const uint4*)(pA + WC * PXS);
      uint4 q11a = *(const uint4*)(pA + WC * PXS + PXS);
      uint4 q00b = *(const uint4*)(pA + 16);
      uint4 q01b = *(const uint4*)(pA + PXS + 16);
      uint4 q10b = *(const uint4*)(pA + WC * PXS + 16);
      uint4 q11b = *(const uint4*)(pA + WC * PXS + PXS + 16);
      short8 Af0 = lerp8(q00a, q01a, q10a, q11a, ww0, ww1, wh0, wh1);
      short8 Af1 = lerp8(q00b, q01b, q10b, q11b, ww0, ww1, wh0, wh1);

      acc[0] = __builtin_amdgcn_mfma_f32_16x16x32_bf16(Af0, b00, acc[0], 0, 0, 0);
      acc[1] = __builtin_amdgcn_mfma_f32_16x16x32_bf16(Af0, b01, acc[1], 0, 0, 0);
      acc[2] = __builtin_amdgcn_mfma_f32_16x16x32_bf16(Af0, b02, acc[2], 0, 0, 0);
      acc[3] = __builtin_amdgcn_mfma_f32_16x16x32_bf16(Af0, b03, acc[3], 0, 0, 0);
      acc[0] = __builtin_amdgcn_mfma_f32_16x16x32_bf16(Af1, b10, acc[0], 0, 0, 0);
      acc[1] = __builtin_amdgcn_mfma_f32_16x16x32_bf16(Af1, b11, acc[1], 0, 0, 0);
      acc[2] = __builtin_amdgcn_mfma_f32_16x16x32_bf16(Af1, b12, acc[2], 0, 0, 0);
      acc[3] = __builtin_amdgcn_mfma_f32_16x16x32_bf16(Af1, b13, acc[3], 0, 0, 0);
    }
  } else {
    // ---- cold exact path (not taken for this data): per-tap global xp gather.
    // FULLY UNROLLED so ph/pw indexing stays static (no scratch allocation). ----
#pragma unroll
    for (int kk = 0; kk < 9; ++kk) {
      float p_h = ph[kk], p_w = pw[kk];
      float fh0 = floorf(p_h), fw0 = floorf(p_w);
      int h0 = (int)fh0, w0 = (int)fw0;
      float wh1 = p_h - fh0, ww1 = p_w - fw0;
      float wh0 = 1.0f - wh1, ww0 = 1.0f - ww1;
      const unsigned* pG = xpb + ((size_t)h0 * WP + w0) * 32 + lq * 4;
      uint4 q00a = *(const uint4*)pG;
      uint4 q01a = *(const uint4*)(pG + 32);
      uint4 q10a = *(const uint4*)(pG + WP * 32);
      uint4 q11a = *(const uint4*)(pG + WP * 32 + 32);
      uint4 q00b = *(const uint4*)(pG + 16);
      uint4 q01b = *(const uint4*)(pG + 48);
      uint4 q10b = *(const uint4*)(pG + WP * 32 + 16);
      uint4 q11b = *(const uint4*)(pG + WP * 32 + 48);
      short8 A0v = lerp8(q00a, q01a, q10a, q11a, ww0, ww1, wh0, wh1);
      short8 A1v = lerp8(q00b, q01b, q10b, q11b, ww0, ww1, wh0, wh1);
      const ushort* bp = wbf + (size_t)kk * 4096 + lane * 8;
      acc[0] = __builtin_amdgcn_mfma_f32_16x16x32_bf16(A0v, *(const short8*)(bp), acc[0], 0, 0, 0);
      acc[1] = __builtin_amdgcn_mfma_f32_16x16x32_bf16(A0v, *(const short8*)(bp + 512), acc[1], 0, 0, 0);
      acc[2] = __builtin_amdgcn_mfma_f32_16x16x32_bf16(A0v, *(const short8*)(bp + 1024), acc[2], 0, 0, 0);
      acc[3] = __builtin_amdgcn_mfma_f32_16x16x32_bf16(A0v, *(const short8*)(bp + 1536), acc[3], 0, 0, 0);
      acc[0] = __builtin_amdgcn_mfma_f32_16x16x32_bf16(A1v, *(const short8*)(bp + 2048), acc[0], 0, 0, 0);
      acc[1] = __builtin_amdgcn_mfma_f32_16x16x32_bf16(A1v, *(const short8*)(bp + 2560), acc[1], 0, 0, 0);
      acc[2] = __builtin_amdgcn_mfma_f32_16x16x32_bf16(A1v, *(const short8*)(bp + 3072), acc[2], 0, 0, 0);
      acc[3] = __builtin_amdgcn_mfma_f32_16x16x32_bf16(A1v, *(const short8*)(bp + 3584), acc[3], 0, 0, 0);
    }
  }

  // ---- epilogue ----
  {
    int px0 = lq * 4;
    int hrow = H0 + 2 * wave + (px0 >> 3);
    int wcol = W0 + (px0 & 7);
#pragma unroll
    for (int nt = 0; nt < 4; ++nt) {
      int o = nt * 16 + lm;
      float bv = bias[o];
      float4 st = make_float4(acc[nt][0] + bv, acc[nt][1] + bv, acc[nt][2] + bv, acc[nt][3] + bv);
      *(float4*)(out + ((size_t)(b * OO + o) * HH + hrow) * WW + wcol) = st;
    }
  }
}

extern "C" void kernel_launch(void* const* d_in, const int* in_sizes, int n_in,
                              void* d_out, int out_size, void* d_ws, size_t ws_size,
                              hipStream_t stream) {
  const float* x        = (const float*)d_in[0];
  const float* weight   = (const float*)d_in[1];
  const float* bias     = (const float*)d_in[2];
  const float* offset_w = (const float*)d_in[3];
  const float* offset_b = (const float*)d_in[4];
  float* out = (float*)d_out;

  unsigned* xp  = (unsigned*)d_ws;                          // 4*131*132*32 uints = 8.85 MB
  ushort* wbf  = (ushort*)(xp + (size_t)BB * HP * WP * 32); // 72*512 ushorts
  ushort* owbf = wbf + (size_t)72 * 512;                    // 36*512 ushorts

  prep_kernel<<<NROW + NZB + NRPK, 256, 0, stream>>>(x, weight, offset_w, xp, wbf, owbf);
  fused_deform<<<1024, 256, 0, stream>>>(xp, wbf, owbf, offset_b, bias, out);
}

// Round 7
// 99.525 us; speedup vs baseline: 1.2040x; 1.0158x over previous
//
#include <hip/hip_runtime.h>

#define BB 4
#define CC 64
#define OO 64
#define HH 128
#define WW 128
#define HP 131          // padded rows (0..130 valid; 0,129,130 zero)
#define WP 132          // padded row width (1..128 data, rest zero)
#define HW (HH*WW)

#define TH 8            // output tile rows per block
#define TW 8            // output tile cols per block
#define WR 15           // staged window rows
#define WC 15           // staged window cols
#define NWIN (WR*WC)    // 225
#define PXS 36          // LDS dwords per window pixel (32 ch-pairs + 4 pad)

typedef __attribute__((ext_vector_type(8))) short short8;
typedef __attribute__((ext_vector_type(4))) float f32x4;

__device__ __forceinline__ unsigned f2b(float f) {  // RNE float->bf16 bits (weight tables)
  unsigned u = __float_as_uint(f);
  return (u + 0x7fffu + ((u >> 16) & 1u)) >> 16;
}
// HW RNE pack: identical rounding to f2b pair, 1 instruction.
__device__ __forceinline__ unsigned cvtpk(float lo, float hi) {
  unsigned r;
  asm("v_cvt_pk_bf16_f32 %0, %1, %2" : "=v"(r) : "v"(lo), "v"(hi));
  return r;
}
__device__ __forceinline__ float blo(unsigned r) { return __uint_as_float(r << 16); }
__device__ __forceinline__ float bhi(unsigned r) { return __uint_as_float(r & 0xffff0000u); }

// prefactored bilinear: val = v00*w00 + v01*w01 + v10*w10 + v11*w11
// (1 mul + 3 fma per channel; weights computed once per tap by caller).
// Pure finite mul/fma reassociation of the round-4 form — cannot produce NaN.
__device__ __forceinline__ short8 lerp8(uint4 q00, uint4 q01, uint4 q10, uint4 q11,
                                        float w00, float w01, float w10, float w11) {
  unsigned c00[4] = {q00.x, q00.y, q00.z, q00.w};
  unsigned c01[4] = {q01.x, q01.y, q01.z, q01.w};
  unsigned c10[4] = {q10.x, q10.y, q10.z, q10.w};
  unsigned c11[4] = {q11.x, q11.y, q11.z, q11.w};
  union { unsigned u[4]; short8 v; } A;
#pragma unroll
  for (int t = 0; t < 4; ++t) {
    float lo = blo(c00[t]) * w00;
    lo = fmaf(blo(c01[t]), w01, lo);
    lo = fmaf(blo(c10[t]), w10, lo);
    lo = fmaf(blo(c11[t]), w11, lo);
    float hi = bhi(c00[t]) * w00;
    hi = fmaf(bhi(c01[t]), w01, hi);
    hi = fmaf(bhi(c10[t]), w10, hi);
    hi = fmaf(bhi(c11[t]), w11, hi);
    A.u[t] = cvtpk(lo, hi);
  }
  return A.v;
}

// ================= prep: row-transpose pad + weight repack, ONE launch =================
// blocks [0,512): one (b,h) source row -> xp[hp][wp][c2] bf16, coalesced both sides
// blocks [512,524): zero rows hp in {0,129,130} x 4 batches
// blocks [524,740): weight repack into MFMA-fragment order
#define NROW (BB*HH)          // 512
#define NZB  12
#define NRPK 216              // (72*512+36*512)/256

__global__ __launch_bounds__(256) void prep_kernel(const float* __restrict__ x,
                                                   const float* __restrict__ wt,
                                                   const float* __restrict__ ow,
                                                   unsigned* __restrict__ xp,
                                                   ushort* __restrict__ wbf,
                                                   ushort* __restrict__ owbf) {
  __shared__ float rbuf[64 * 129];   // stride 129: bank = (c+w)%32 -> 2-way max (free)
  int bid = blockIdx.x;
  int tid = threadIdx.x;

  if (bid < NROW) {
    int b = bid >> 7, h = bid & 127;
    const float* xs = x + ((size_t)b * CC * HH + h) * WW;  // element (c,w) at c*HW + w
#pragma unroll
    for (int it = 0; it < 32; ++it) {          // 64*128 floats, coalesced 256B runs
      int idx = it * 256 + tid;
      int c = idx >> 7, w = idx & 127;
      rbuf[c * 129 + w] = xs[(size_t)c * HW + w];
    }
    __syncthreads();
    int hp = h + 1;
    unsigned* xrow = xp + (size_t)b * (HP * WP * 32) + (size_t)hp * (WP * 32);
#pragma unroll
    for (int it = 0; it < 5; ++it) {           // 132 wp * 8 c8 uint4 writes, coalesced
      int q = it * 256 + tid;
      if (q < WP * 8) {
        int wp = q >> 3, c8 = q & 7;
        uint4 v = make_uint4(0, 0, 0, 0);
        if (wp >= 1 && wp <= WW) {
          const float* rp = &rbuf[(c8 * 8) * 129 + (wp - 1)];
          v.x = cvtpk(rp[0], rp[129]);
          v.y = cvtpk(rp[2 * 129], rp[3 * 129]);
          v.z = cvtpk(rp[4 * 129], rp[5 * 129]);
          v.w = cvtpk(rp[6 * 129], rp[7 * 129]);
        }
        *(uint4*)(xrow + (size_t)wp * 32 + c8 * 4) = v;
      }
    }
  } else if (bid < NROW + NZB) {
    int z = bid - NROW;
    int b = z / 3, r = z % 3;
    int hp = (r == 0) ? 0 : ((r == 1) ? 129 : 130);
    unsigned* xrow = xp + (size_t)b * (HP * WP * 32) + (size_t)hp * (WP * 32);
    for (int q = tid; q < WP * 8; q += 256)
      *(uint4*)(xrow + (size_t)(q >> 3) * 32 + (q & 7) * 4) = make_uint4(0, 0, 0, 0);
  } else {
    int i = (bid - NROW - NZB) * 256 + tid;
    if (i < 72 * 512) {
      int j = i & 7, lane = (i >> 3) & 63, T = i >> 9;
      int nt = T & 3, sh = (T >> 2) & 1, kk = T >> 3;
      int o = nt * 16 + (lane & 15);
      int c = sh * 32 + (lane >> 4) * 8 + j;
      wbf[i] = (ushort)f2b(wt[(o * CC + c) * 9 + kk]);
    } else if (i < 72 * 512 + 36 * 512) {
      int i2 = i - 72 * 512;
      int j = i2 & 7, lane = (i2 >> 3) & 63, T = i2 >> 9;
      int nt = T & 1, sh = (T >> 1) & 1, kk = T >> 2;
      int oc = nt * 16 + (lane & 15);
      int c = sh * 32 + (lane >> 4) * 8 + j;
      owbf[i2] = (oc < 18) ? (ushort)f2b(ow[(oc * CC + c) * 9 + kk]) : (ushort)0;
    }
  }
}

// ---------------- fused: stage window -> offs GEMM -> deform GEMM ----------------
// vs round-4 (passing): TWO changes, register B-pipeline permanently ABANDONED
// (NaN in rounds 2/5/6; round 6 isolated it as the sole NaN-capable variable):
// (1) post-obuf __syncthreads removed: the obuf transpose is wave-local (wave w
//     writes+reads rows [16w,16w+16)); in-wave DS ops complete in order and the
//     store/load indices MayAlias so the compiler preserves their order;
//     sched_barrier(0) additionally pins the schedulers. Waves decouple for the
//     whole gather/lerp/GEMM phase.
// (2) prefactored bilinear weights (17 ops/dword vs 21).
__global__ __launch_bounds__(256, 4) void fused_deform(const unsigned* __restrict__ xp,
                                                       const ushort* __restrict__ wbf,
                                                       const ushort* __restrict__ owbf,
                                                       const float* __restrict__ obias,
                                                       const float* __restrict__ bias,
                                                       float* __restrict__ out) {
  __shared__ __align__(16) unsigned win[NWIN * PXS];   // 32.4 KB
  __shared__ __align__(16) float obuf[64 * 20];        // 5.1 KB

  int tid = threadIdx.x;
  int blk0 = blockIdx.x;
  int xcd = blk0 & 7, i = blk0 >> 3;
  int s = xcd * 8 + (i >> 4);            // slab 0..63 = b*16 + ht
  int b = s >> 4, ht = s & 15, wtile = i & 15;
  int H0 = ht * TH, W0 = wtile * TW;
  int rlo = H0 - 1, clo = W0 - 1;        // window origin, padded coords

  int wave = tid >> 6, lane = tid & 63, lm = lane & 15, lq = lane >> 4;
  const unsigned* xpb = xp + (size_t)b * (HP * WP * 32);

  // ---- stage window: batch all global loads, then all LDS writes ----
  {
    uint4 sv[8];
#pragma unroll
    for (int it = 0; it < 8; ++it) {
      int q = tid + it * 256;
      uint4 v = make_uint4(0, 0, 0, 0);
      if (q < NWIN * 8) {
        int px = q >> 3;
        int r = px / WC, c = px % WC;
        int pr = rlo + r, pc = clo + c;
        if (pr >= 0 && pr <= HP - 1 && pc >= 0 && pc <= WP - 2)
          v = *(const uint4*)(xpb + ((size_t)pr * WP + pc) * 32 + (q & 7) * 4);
      }
      sv[it] = v;
    }
#pragma unroll
    for (int it = 0; it < 8; ++it) {
      int q = tid + it * 256;
      if (q < NWIN * 8) {
        int px = q >> 3, ch = q & 7;
        *(uint4*)&win[px * PXS + ch * 4] = sv[it];
      }
    }
  }
  __syncthreads();                       // win is block-shared: this barrier stays

  int row = 2 * wave + (lm >> 3);        // tile-local pixel coords for lane lm
  int col = lm & 7;
  int h = H0 + row, w = W0 + col;

  // ---- offs GEMM, kk-outer: 4 batched B loads + 2 LDS A reads + 4 MFMAs ----
  {
    f32x4 oacc0 = (f32x4)0.0f, oacc1 = (f32x4)0.0f;
#pragma unroll
    for (int kk = 0; kk < 9; ++kk) {
      const ushort* obp = owbf + (size_t)(kk * 4) * 512 + lane * 8;
      short8 ob00 = *(const short8*)(obp);            // sh0,nt0
      short8 ob01 = *(const short8*)(obp + 512);      // sh0,nt1
      short8 ob10 = *(const short8*)(obp + 1024);     // sh1,nt0
      short8 ob11 = *(const short8*)(obp + 1536);     // sh1,nt1
      int kh = kk / 3, kw = kk % 3;
      int widx = (row + kh + 1) * WC + (col + kw + 1);
      const unsigned* wp0 = &win[widx * PXS + lq * 4];
      short8 Ao0 = *(const short8*)wp0;
      short8 Ao1 = *(const short8*)(wp0 + 16);
      oacc0 = __builtin_amdgcn_mfma_f32_16x16x32_bf16(Ao0, ob00, oacc0, 0, 0, 0);
      oacc1 = __builtin_amdgcn_mfma_f32_16x16x32_bf16(Ao0, ob01, oacc1, 0, 0, 0);
      oacc0 = __builtin_amdgcn_mfma_f32_16x16x32_bf16(Ao1, ob10, oacc0, 0, 0, 0);
      oacc1 = __builtin_amdgcn_mfma_f32_16x16x32_bf16(Ao1, ob11, oacc1, 0, 0, 0);
    }
    // wave-local transpose: wave w writes only rows [16w,16w+16) and reads only
    // those rows below -> no block barrier needed.
#pragma unroll
    for (int nt = 0; nt < 2; ++nt) {
      f32x4 oa = nt ? oacc1 : oacc0;
      int oc = nt * 16 + lm;
      if (oc < 18) {
        float bv = obias[oc];
        int idx = (oc < 9) ? (oc * 2) : ((oc - 9) * 2 + 1);
#pragma unroll
        for (int r2 = 0; r2 < 4; ++r2)
          obuf[(wave * 16 + lq * 4 + r2) * 20 + idx] = oa[r2] + bv;
      }
    }
  }
  __builtin_amdgcn_sched_barrier(0);     // pin write->read order (no reconvergence)

  // ---- positions once (statically indexed everywhere -> registers) ----
  float ph[9], pw[9];
  bool okall = true;
  {
    float orow[20];
    const float* orp = &obuf[(wave * 16 + lm) * 20];
#pragma unroll
    for (int q = 0; q < 5; ++q) *(float4*)&orow[q * 4] = *(const float4*)(orp + q * 4);
#pragma unroll
    for (int kk = 0; kk < 9; ++kk) {
      int kh = kk / 3, kw = kk % 3;
      float p_h = (((float)kh + orow[kk * 2]) + (float)h) + 1.0f;
      float p_w = (((float)kw + orow[kk * 2 + 1]) + (float)w) + 1.0f;
      p_h = fminf(fmaxf(p_h, 0.0f), 129.0f);
      p_w = fminf(fmaxf(p_w, 0.0f), 129.0f);
      ph[kk] = p_h;
      pw[kk] = p_w;
      int h0 = (int)floorf(p_h), w0 = (int)floorf(p_w);
      int wr0 = h0 - rlo, wc0 = w0 - clo;
      okall &= (wr0 >= 0) & (wr0 <= WR - 2) & (wc0 >= 0) & (wc0 <= WC - 2);
    }
  }

  f32x4 acc[4];
#pragma unroll
  for (int nt = 0; nt < 4; ++nt) acc[nt] = (f32x4)0.0f;

  if (__builtin_amdgcn_ballot_w64(okall) == ~0ull) {
    // ---- fast path, kk-outer: 8 B loads batched before gather+lerp ----
#pragma unroll
    for (int kk = 0; kk < 9; ++kk) {
      const ushort* bp = wbf + (size_t)kk * 4096 + lane * 8;
      short8 b00 = *(const short8*)(bp);
      short8 b01 = *(const short8*)(bp + 512);
      short8 b02 = *(const short8*)(bp + 1024);
      short8 b03 = *(const short8*)(bp + 1536);
      short8 b10 = *(const short8*)(bp + 2048);
      short8 b11 = *(const short8*)(bp + 2560);
      short8 b12 = *(const short8*)(bp + 3072);
      short8 b13 = *(const short8*)(bp + 3584);

      float p_h = ph[kk], p_w = pw[kk];
      float fh0 = floorf(p_h), fw0 = floorf(p_w);
      int h0 = (int)fh0, w0 = (int)fw0;
      float wh1 = p_h - fh0, ww1 = p_w - fw0;
      float wh0 = 1.0f - wh1, ww0 = 1.0f - ww1;
      float w00 = wh0 * ww0, w01 = wh0 * ww1, w10 = wh1 * ww0, w11 = wh1 * ww1;
      const unsigned* pA = &win[((h0 - rlo) * WC + (w0 - clo)) * PXS + lq * 4];
      uint4 q00a = *(const uint4*)pA;
      uint4 q01a = *(const uint4*)(pA + PXS);
      uint4 q10a = *(const uint4*)(pA + WC * PXS);
      uint4 q11a = *(const uint4*)(pA + WC * PXS + PXS);
      uint4 q00b = *(const uint4*)(pA + 16);
      uint4 q01b = *(const uint4*)(pA + PXS + 16);
      uint4 q10b = *(const uint4*)(pA + WC * PXS + 16);
      uint4 q11b = *(const uint4*)(pA + WC * PXS + PXS + 16);
      short8 Af0 = lerp8(q00a, q01a, q10a, q11a, w00, w01, w10, w11);
      short8 Af1 = lerp8(q00b, q01b, q10b, q11b, w00, w01, w10, w11);

      acc[0] = __builtin_amdgcn_mfma_f32_16x16x32_bf16(Af0, b00, acc[0], 0, 0, 0);
      acc[1] = __builtin_amdgcn_mfma_f32_16x16x32_bf16(Af0, b01, acc[1], 0, 0, 0);
      acc[2] = __builtin_amdgcn_mfma_f32_16x16x32_bf16(Af0, b02, acc[2], 0, 0, 0);
      acc[3] = __builtin_amdgcn_mfma_f32_16x16x32_bf16(Af0, b03, acc[3], 0, 0, 0);
      acc[0] = __builtin_amdgcn_mfma_f32_16x16x32_bf16(Af1, b10, acc[0], 0, 0, 0);
      acc[1] = __builtin_amdgcn_mfma_f32_16x16x32_bf16(Af1, b11, acc[1], 0, 0, 0);
      acc[2] = __builtin_amdgcn_mfma_f32_16x16x32_bf16(Af1, b12, acc[2], 0, 0, 0);
      acc[3] = __builtin_amdgcn_mfma_f32_16x16x32_bf16(Af1, b13, acc[3], 0, 0, 0);
    }
  } else {
    // ---- cold exact path (not taken for this data): per-tap global xp gather.
    // FULLY UNROLLED so ph/pw indexing stays static (no scratch allocation). ----
#pragma unroll
    for (int kk = 0; kk < 9; ++kk) {
      float p_h = ph[kk], p_w = pw[kk];
      float fh0 = floorf(p_h), fw0 = floorf(p_w);
      int h0 = (int)fh0, w0 = (int)fw0;
      float wh1 = p_h - fh0, ww1 = p_w - fw0;
      float wh0 = 1.0f - wh1, ww0 = 1.0f - ww1;
      float w00 = wh0 * ww0, w01 = wh0 * ww1, w10 = wh1 * ww0, w11 = wh1 * ww1;
      const unsigned* pG = xpb + ((size_t)h0 * WP + w0) * 32 + lq * 4;
      uint4 q00a = *(const uint4*)pG;
      uint4 q01a = *(const uint4*)(pG + 32);
      uint4 q10a = *(const uint4*)(pG + WP * 32);
      uint4 q11a = *(const uint4*)(pG + WP * 32 + 32);
      uint4 q00b = *(const uint4*)(pG + 16);
      uint4 q01b = *(const uint4*)(pG + 48);
      uint4 q10b = *(const uint4*)(pG + WP * 32 + 16);
      uint4 q11b = *(const uint4*)(pG + WP * 32 + 48);
      short8 A0v = lerp8(q00a, q01a, q10a, q11a, w00, w01, w10, w11);
      short8 A1v = lerp8(q00b, q01b, q10b, q11b, w00, w01, w10, w11);
      const ushort* bp = wbf + (size_t)kk * 4096 + lane * 8;
      acc[0] = __builtin_amdgcn_mfma_f32_16x16x32_bf16(A0v, *(const short8*)(bp), acc[0], 0, 0, 0);
      acc[1] = __builtin_amdgcn_mfma_f32_16x16x32_bf16(A0v, *(const short8*)(bp + 512), acc[1], 0, 0, 0);
      acc[2] = __builtin_amdgcn_mfma_f32_16x16x32_bf16(A0v, *(const short8*)(bp + 1024), acc[2], 0, 0, 0);
      acc[3] = __builtin_amdgcn_mfma_f32_16x16x32_bf16(A0v, *(const short8*)(bp + 1536), acc[3], 0, 0, 0);
      acc[0] = __builtin_amdgcn_mfma_f32_16x16x32_bf16(A1v, *(const short8*)(bp + 2048), acc[0], 0, 0, 0);
      acc[1] = __builtin_amdgcn_mfma_f32_16x16x32_bf16(A1v, *(const short8*)(bp + 2560), acc[1], 0, 0, 0);
      acc[2] = __builtin_amdgcn_mfma_f32_16x16x32_bf16(A1v, *(const short8*)(bp + 3072), acc[2], 0, 0, 0);
      acc[3] = __builtin_amdgcn_mfma_f32_16x16x32_bf16(A1v, *(const short8*)(bp + 3584), acc[3], 0, 0, 0);
    }
  }

  // ---- epilogue ----
  {
    int px0 = lq * 4;
    int hrow = H0 + 2 * wave + (px0 >> 3);
    int wcol = W0 + (px0 & 7);
#pragma unroll
    for (int nt = 0; nt < 4; ++nt) {
      int o = nt * 16 + lm;
      float bv = bias[o];
      float4 st = make_float4(acc[nt][0] + bv, acc[nt][1] + bv, acc[nt][2] + bv, acc[nt][3] + bv);
      *(float4*)(out + ((size_t)(b * OO + o) * HH + hrow) * WW + wcol) = st;
    }
  }
}

extern "C" void kernel_launch(void* const* d_in, const int* in_sizes, int n_in,
                              void* d_out, int out_size, void* d_ws, size_t ws_size,
                              hipStream_t stream) {
  const float* x        = (const float*)d_in[0];
  const float* weight   = (const float*)d_in[1];
  const float* bias     = (const float*)d_in[2];
  const float* offset_w = (const float*)d_in[3];
  const float* offset_b = (const float*)d_in[4];
  float* out = (float*)d_out;

  unsigned* xp  = (unsigned*)d_ws;                          // 4*131*132*32 uints = 8.85 MB
  ushort* wbf  = (ushort*)(xp + (size_t)BB * HP * WP * 32); // 72*512 ushorts
  ushort* owbf = wbf + (size_t)72 * 512;                    // 36*512 ushorts

  prep_kernel<<<NROW + NZB + NRPK, 256, 0, stream>>>(x, weight, offset_w, xp, wbf, owbf);
  fused_deform<<<1024, 256, 0, stream>>>(xp, wbf, owbf, offset_b, bias, out);
}